// Round 6
// baseline (314.587 us; speedup 1.0000x reference)
//
#include <hip/hip_runtime.h>
#include <math.h>

#define HID 16
#define KNN 16
#define NB 64          // graphs
#define NTS 8192
#define NLC 12288
#define TSG 128        // ts rows per graph
#define LCG 192        // lc rows per graph

__device__ __forceinline__ float eluf(float x) {
    return x > 0.0f ? x : expm1f(x);
}

// monotone map float -> uint32 (total order matches float <, incl. negatives)
__device__ __forceinline__ unsigned int f2ord(float f) {
    unsigned int b = __float_as_uint(f);
    return b ^ (((int)b >> 31) | 0x80000000u);
}

// ---------------------------------------------------------------- encoders
// 4 THREADS PER ROW (R5 was 1 thread/row at 80 blocks = 0.3 waves/SIMD,
// latency-starved). 320 blocks x 256 threads = 1280 waves. Hidden vector
// relayed through LDS; all accumulations k-ascending -> bit-identical to
// R5 (encoder outputs feed kNN distance ties, must not perturb).
// Blocks 0..127 -> ts rows, 128..319 -> lc rows. Also zeroes pooled + ctr.
__global__ __launch_bounds__(256) void encode_kernel(
    const float* __restrict__ x_ts, const float* __restrict__ x_lc,
    const float* __restrict__ ts_w1, const float* __restrict__ ts_b1,
    const float* __restrict__ ts_w2, const float* __restrict__ ts_b2,
    const float* __restrict__ lc_w1, const float* __restrict__ lc_b1,
    const float* __restrict__ lc_w2, const float* __restrict__ lc_b2,
    const float* __restrict__ cw,
    float* __restrict__ ts_enc, float* __restrict__ lc_enc,
    float* __restrict__ y_lc, float* __restrict__ n_lc,
    float* __restrict__ pooled, int* __restrict__ ctr)
{
    __shared__ float sw1[6 * HID];
    __shared__ float sw2[HID * HID];
    __shared__ float scw2[HID * HID];   // conv W2 (lc blocks only)
    __shared__ float sb1[HID];
    __shared__ float sb2[HID];
    __shared__ float s_h[64 * 17];      // 64 rows/block, padded

    const int tid = threadIdx.x;
    const int t = blockIdx.x * 256 + tid;
    if (t < NB * HID) pooled[t] = 0.0f;   // zero pool accumulator (0xAA-poisoned)
    if (t == NB * HID) *ctr = 0;          // zero conv3 completion counter

    const bool is_ts = (blockIdx.x < NTS / 64);   // 128 ts blocks
    const float* w1 = is_ts ? ts_w1 : lc_w1;
    const float* b1 = is_ts ? ts_b1 : lc_b1;
    const float* w2 = is_ts ? ts_w2 : lc_w2;
    const float* b2 = is_ts ? ts_b2 : lc_b2;
    const int in_dim = is_ts ? 6 : 5;

    if (tid < in_dim * HID) sw1[tid] = w1[tid];
    if (tid < HID * HID)    sw2[tid] = w2[tid];
    if (!is_ts && tid < HID * HID) scw2[tid] = cw[HID * HID + tid];
    if (tid < HID)          { sb1[tid] = b1[tid]; sb2[tid] = b2[tid]; }
    __syncthreads();

    const int q    = tid & 3;          // channel quad: channels 4q..4q+3
    const int rloc = tid >> 2;         // local row 0..63
    const int row  = is_ts ? (blockIdx.x * 64 + rloc)
                           : ((blockIdx.x - 128) * 64 + rloc);
    const float* x = is_ts ? (x_ts + (size_t)row * 6) : (x_lc + (size_t)row * 5);
    float* outp    = is_ts ? (ts_enc + (size_t)row * HID) : (lc_enc + (size_t)row * HID);

    float xin[6];
    for (int k = 0; k < in_dim; ++k) xin[k] = x[k];

    // layer 1: this thread's 4 channels (same per-channel k order as before)
    #pragma unroll
    for (int jc = 0; jc < 4; ++jc) {
        const int c = 4 * q + jc;
        float s = sb1[c];
        for (int k = 0; k < in_dim; ++k) s += xin[k] * sw1[k * HID + c];
        s_h[rloc * 17 + c] = eluf(s);
    }
    __syncthreads();
    float hf[HID];
    #pragma unroll
    for (int k = 0; k < HID; ++k) hf[k] = s_h[rloc * 17 + k];

    // layer 2
    float o4v[4];
    #pragma unroll
    for (int jc = 0; jc < 4; ++jc) {
        const int c = 4 * q + jc;
        float s = sb2[c];
        #pragma unroll
        for (int k = 0; k < HID; ++k) s += hf[k] * sw2[k * HID + c];
        o4v[jc] = eluf(s);
    }
    reinterpret_cast<float4*>(outp)[q] = make_float4(o4v[0], o4v[1], o4v[2], o4v[3]);

    if (!is_ts) {
        __syncthreads();   // done reading s_h (layer1); reuse for o relay
        #pragma unroll
        for (int jc = 0; jc < 4; ++jc) s_h[rloc * 17 + 4 * q + jc] = o4v[jc];
        __syncthreads();
        float of[HID];
        #pragma unroll
        for (int k = 0; k < HID; ++k) of[k] = s_h[rloc * 17 + k];
        float nv = 0.f;
        #pragma unroll
        for (int c = 0; c < HID; ++c) nv += of[c] * of[c];   // c ascending (exact self-dist 0)
        float y4[4];
        #pragma unroll
        for (int jc = 0; jc < 4; ++jc) {
            const int c = 4 * q + jc;
            float s = 0.f;
            #pragma unroll
            for (int k = 0; k < HID; ++k) s += of[k] * scw2[k * HID + c];
            y4[jc] = s;
        }
        reinterpret_cast<float4*>(y_lc + (size_t)row * HID)[q] =
            make_float4(y4[0], y4[1], y4[2], y4[3]);
        if (q == 0) n_lc[row] = nv;
    }
}

// ------------------------------------------------------------ edge conv
// ONE WAVE PER DST ROW; block = 512 threads = 8 dst rows of one graph.
// y = src@W2 and ||src||^2 precomputed. Lane keeps its 3 src rows
// {l, l+64, l+128} in registers. Top-16 SET via ballot-radix select
// (pure VALU/SALU — R5 win vs shuffle tournament), exact top_k tie-break.
#define CONV_SMEM_FLOATS (LCG * HID + 2 * HID * HID + 2 * HID)
#define CONV_SMEM_BYTES  (CONV_SMEM_FLOATS * 4)

template<int NSRC, int NDST, bool POOL, bool EPI>
__device__ __forceinline__ void edgeconv_impl(
    float* __restrict__ smem, int bid,
    const float* __restrict__ src, const float* __restrict__ src_y,
    const float* __restrict__ src_n, const float* __restrict__ dst,
    const float* __restrict__ cw, const float* __restrict__ cb,
    float* __restrict__ out_feats, float* __restrict__ out_y,
    float* __restrict__ out_n, float* __restrict__ pool_out)
{
    constexpr int RPB = 8;              // dst rows (waves) per block
    constexpr int BPG = NDST / RPB;     // blocks per graph
    float* s_y    = smem;                        // NSRC*HID
    float* s_dw   = s_y + NSRC * HID;            // 256  (W1 - W2)
    float* s_w2   = s_dw + HID * HID;            // 256  (EPI only)
    float* s_b    = s_w2 + HID * HID;            // 16
    float* s_pool = s_b + HID;                   // 16

    const int tid  = threadIdx.x;
    const int lane = tid & 63;
    const int wave = tid >> 6;
    const int g      = bid / BPG;
    const int rowblk = bid % BPG;

    // ---- stage weights + y (coalesced float4)
    if (tid < HID * HID) {
        float w1v = cw[tid];
        float w2v = cw[HID * HID + tid];
        s_dw[tid] = w1v - w2v;
        if (EPI) s_w2[tid] = w2v;
    }
    if (tid < HID) s_b[tid] = cb[tid];
    if (POOL && tid < HID) s_pool[tid] = 0.0f;
    {
        const float4* gy = reinterpret_cast<const float4*>(src_y + (size_t)(g * NSRC) * HID);
        float4* sy4 = reinterpret_cast<float4*>(s_y);
        for (int i = tid; i < NSRC * HID / 4; i += 512) sy4[i] = gy[i];
    }

    // ---- own src rows + norms -> registers
    float rw[3][HID];
    float rn[3];
    #pragma unroll
    for (int k = 0; k < 3; ++k) {
        const float4* rp = reinterpret_cast<const float4*>(src + (size_t)(g * NSRC + lane + 64 * k) * HID);
        float4 a = rp[0], b = rp[1], c4 = rp[2], e = rp[3];
        rw[k][0] = a.x;  rw[k][1] = a.y;  rw[k][2]  = a.z;  rw[k][3]  = a.w;
        rw[k][4] = b.x;  rw[k][5] = b.y;  rw[k][6]  = b.z;  rw[k][7]  = b.w;
        rw[k][8] = c4.x; rw[k][9] = c4.y; rw[k][10] = c4.z; rw[k][11] = c4.w;
        rw[k][12] = e.x; rw[k][13] = e.y; rw[k][14] = e.z;  rw[k][15] = e.w;
        rn[k] = src_n[g * NSRC + lane + 64 * k];
    }

    // ---- my wave's dst row
    const int drow = rowblk * RPB + wave;
    const float4* d4 = reinterpret_cast<const float4*>(dst + (size_t)(g * NDST + drow) * HID);
    float xi[HID];
    {
        float4 a = d4[0], b = d4[1], c4 = d4[2], e = d4[3];
        xi[0] = a.x;  xi[1] = a.y;  xi[2]  = a.z;  xi[3]  = a.w;
        xi[4] = b.x;  xi[5] = b.y;  xi[6]  = b.z;  xi[7]  = b.w;
        xi[8] = c4.x; xi[9] = c4.y; xi[10] = c4.z; xi[11] = c4.w;
        xi[12] = e.x; xi[13] = e.y; xi[14] = e.z;  xi[15] = e.w;
    }
    float nd = 0.f;
    #pragma unroll
    for (int c = 0; c < HID; ++c) nd += xi[c] * xi[c];

    // ---- 3 candidate distances as ordered-u32 (idx implicit: lane + 64k)
    unsigned int dk0, dk1, dk2;
    {
        unsigned int dk[3];
        #pragma unroll
        for (int k = 0; k < 3; ++k) {
            float dot = 0.f;
            #pragma unroll
            for (int c = 0; c < HID; ++c) dot += xi[c] * rw[k][c];
            dk[k] = f2ord(nd - 2.0f * dot + rn[k]);
        }
        dk0 = dk[0]; dk1 = dk[1]; dk2 = dk[2];
    }

    // ---- ballot-radix select of the 16th-smallest (dist, idx) key
    unsigned int p = 0;
    int k = KNN;
    for (int b = 31; b >= 0; --b) {
        unsigned int pb = p >> b;
        int cnt = __popcll(__ballot((dk0 >> b) == pb))
                + __popcll(__ballot((dk1 >> b) == pb))
                + __popcll(__ballot((dk2 >> b) == pb));
        if (k > cnt) { k -= cnt; p |= (1u << b); }
    }
    int cnt_eq = __popcll(__ballot(dk0 == p))
               + __popcll(__ballot(dk1 == p))
               + __popcll(__ballot(dk2 == p));
    unsigned int qi = 255u;              // idx cutoff within eq class
    if (cnt_eq != k) {                   // rare exact-dist tie at the boundary
        qi = 0;
        int kk = k;
        const unsigned int i0 = (unsigned)lane, i1 = (unsigned)(lane + 64), i2 = (unsigned)(lane + 128);
        for (int b = 7; b >= 0; --b) {
            unsigned int qb = qi >> b;
            int cnt = __popcll(__ballot(dk0 == p && (i0 >> b) == qb))
                    + __popcll(__ballot(dk1 == p && (i1 >> b) == qb))
                    + __popcll(__ballot(dk2 == p && (i2 >> b) == qb));
            if (kk > cnt) { kk -= cnt; qi |= (1u << b); }
        }
    }
    unsigned long long m0 = __ballot(dk0 < p || (dk0 == p && (unsigned)lane <= qi));
    unsigned long long m1 = __ballot(dk1 < p || (dk1 == p && (unsigned)(lane + 64) <= qi));
    unsigned long long m2 = __ballot(dk2 < p || (dk2 == p && (unsigned)(lane + 128) <= qi));

    __syncthreads();   // s_y / s_dw ready

    // ci = b + xi @ (W1 - W2); lane handles channel c = lane & 15
    const int c = lane & 15;
    float cic = s_b[c];
    #pragma unroll
    for (int r = 0; r < HID; ++r) cic += xi[r] * s_dw[r * HID + c];

    // ---- winner indices (SALU, wave-uniform), then 16 independent y reads
    int jarr[KNN];
    #pragma unroll
    for (int i = 0; i < KNN; ++i) {
        int j;
        if (m0)      { j = __builtin_ctzll(m0);       m0 &= m0 - 1; }
        else if (m1) { j = 64 + __builtin_ctzll(m1);  m1 &= m1 - 1; }
        else         { j = 128 + __builtin_ctzll(m2); m2 &= m2 - 1; }
        jarr[i] = j;
    }
    float yv[KNN];
    #pragma unroll
    for (int i = 0; i < KNN; ++i) yv[i] = s_y[jarr[i] * HID + c];
    float ym = yv[0];
    #pragma unroll
    for (int i = 1; i < KNN; ++i) ym = fmaxf(ym, yv[i]);

    const float f = eluf(cic + ym);   // == max_j elu(ci + y_j), exact

    if (POOL) {
        if (lane < HID) atomicAdd(&s_pool[c], f);
        __syncthreads();
        if (tid < HID) atomicAdd(&pool_out[g * HID + tid], s_pool[tid]);
    } else {
        const int grow = g * NDST + drow;
        if (lane < HID) out_feats[(size_t)grow * HID + c] = f;
        if (EPI) {
            float yvv = 0.f, nv = 0.f;
            #pragma unroll
            for (int r = 0; r < HID; ++r) {
                float fr = __shfl(f, r, 64);   // lane r holds channel r
                yvv += fr * s_w2[r * HID + c];
                nv += fr * fr;
            }
            if (lane < HID) out_y[(size_t)grow * HID + c] = yvv;
            if (lane == 0)  out_n[grow] = nv;
        }
    }
}

// conv1 (lc->lc, emits y/n for conv3) and conv2 (lc->ts): independent -> one dispatch.
#define C1_BLOCKS (NB * (LCG / 8))   // 1536
#define C2_BLOCKS (NB * (TSG / 8))   // 1024
__global__ __launch_bounds__(512) void edgeconv12_kernel(
    const float* __restrict__ lc_enc, const float* __restrict__ y_lc,
    const float* __restrict__ n_lc, const float* __restrict__ ts_enc,
    const float* __restrict__ cw, const float* __restrict__ cb,
    float* __restrict__ feats1, float* __restrict__ y_f1, float* __restrict__ n_f1,
    float* __restrict__ feats2)
{
    extern __shared__ float smem[];
    if (blockIdx.x < C1_BLOCKS)
        edgeconv_impl<LCG, LCG, false, true>(smem, blockIdx.x, lc_enc, y_lc, n_lc,
                                             lc_enc, cw, cb, feats1, y_f1, n_f1, nullptr);
    else
        edgeconv_impl<LCG, TSG, false, false>(smem, blockIdx.x - C1_BLOCKS, lc_enc, y_lc, n_lc,
                                              ts_enc, cw, cb, feats2, nullptr, nullptr, nullptr);
}

// conv3 + FUSED HEAD: last-finished block (device-scope counter; pooled
// atomics drained by __syncthreads' vmcnt(0) before the counter bump) runs
// all 64 graph-heads: 8 waves x per-wave LDS slice, 8 iterations.
// Accumulation r-ascending == old head_kernel -> bit-exact.
__global__ __launch_bounds__(512) void edgeconv3_kernel(
    const float* __restrict__ feats1, const float* __restrict__ y_f1,
    const float* __restrict__ n_f1, const float* __restrict__ feats2,
    const float* __restrict__ cw, const float* __restrict__ cb,
    float* __restrict__ pooled, int* __restrict__ ctr,
    const float* __restrict__ w1, const float* __restrict__ b1,
    const float* __restrict__ w2, const float* __restrict__ b2,
    const float* __restrict__ w3, const float* __restrict__ b3,
    const float* __restrict__ w4, const float* __restrict__ b4,
    const float* __restrict__ w5, const float* __restrict__ b5,
    float* __restrict__ out)
{
    extern __shared__ float smem[];
    edgeconv_impl<LCG, TSG, true, false>(smem, blockIdx.x, feats1, y_f1, n_f1,
                                         feats2, cw, cb, nullptr, nullptr, nullptr, pooled);

    __threadfence();
    __shared__ int s_last;
    if (threadIdx.x == 0)
        s_last = (atomicAdd(ctr, 1) == C2_BLOCKS - 1) ? 1 : 0;
    __syncthreads();
    if (!s_last) return;
    __threadfence();   // acquire: all blocks' pooled atomics visible

    const int lane = threadIdx.x & 63;
    const int wave = threadIdx.x >> 6;
    float* hs = smem + wave * 128;   // sp@0[16] h1@16[64] h2@80[32] h3@112[8] h4@120[4]

    for (int it = 0; it < 8; ++it) {
        const int g = it * 8 + wave;
        if (lane < HID) hs[lane] = pooled[g * HID + lane] * (1.0f / (float)TSG);
        __syncthreads();
        {
            float s = b1[lane];
            #pragma unroll
            for (int r = 0; r < HID; ++r) s += hs[r] * w1[r * 64 + lane];
            hs[16 + lane] = eluf(s);
        }
        __syncthreads();
        if (lane < 32) {
            float s = b2[lane];
            #pragma unroll
            for (int r = 0; r < 64; ++r) s += hs[16 + r] * w2[r * 32 + lane];
            hs[80 + lane] = eluf(s);
        }
        __syncthreads();
        if (lane < 8) {
            float s = b3[lane];
            #pragma unroll
            for (int r = 0; r < 32; ++r) s += hs[80 + r] * w3[r * 8 + lane];
            hs[112 + lane] = eluf(s);
        }
        __syncthreads();
        if (lane < 4) {
            float s = b4[lane];
            #pragma unroll
            for (int r = 0; r < 8; ++r) s += hs[112 + r] * w4[r * 4 + lane];
            hs[120 + lane] = eluf(s);
        }
        __syncthreads();
        if (lane == 0) {
            float s = b5[0];
            #pragma unroll
            for (int r = 0; r < 4; ++r) s += hs[120 + r] * w5[r];
            out[g] = s;
            out[NB + g] = (float)g;   // batch_out = arange(B)
        }
        __syncthreads();
    }
}

// ---------------------------------------------------------------- launch
extern "C" void kernel_launch(void* const* d_in, const int* in_sizes, int n_in,
                              void* d_out, int out_size, void* d_ws, size_t ws_size,
                              hipStream_t stream) {
    const float* x_ts  = (const float*)d_in[0];
    const float* x_lc  = (const float*)d_in[1];
    // d_in[2], d_in[3]: batch arrays — contiguous repeat(arange(64)), layout hard-coded
    const float* ts_w1 = (const float*)d_in[4];
    const float* ts_b1 = (const float*)d_in[5];
    const float* ts_w2 = (const float*)d_in[6];
    const float* ts_b2 = (const float*)d_in[7];
    const float* lc_w1 = (const float*)d_in[8];
    const float* lc_b1 = (const float*)d_in[9];
    const float* lc_w2 = (const float*)d_in[10];
    const float* lc_b2 = (const float*)d_in[11];
    const float* cw    = (const float*)d_in[12];
    const float* cb    = (const float*)d_in[13];
    const float* ow1   = (const float*)d_in[14];
    const float* ob1   = (const float*)d_in[15];
    const float* ow2   = (const float*)d_in[16];
    const float* ob2   = (const float*)d_in[17];
    const float* ow3   = (const float*)d_in[18];
    const float* ob3   = (const float*)d_in[19];
    const float* ow4   = (const float*)d_in[20];
    const float* ob4   = (const float*)d_in[21];
    const float* ow5   = (const float*)d_in[22];
    const float* ob5   = (const float*)d_in[23];
    float* out = (float*)d_out;

    float* ws = (float*)d_ws;
    float* ts_enc = ws;                       // 8192*16  = 131072
    float* lc_enc = ws + 131072;              // 12288*16 = 196608
    float* feats1 = ws + 327680;              // 12288*16 = 196608
    float* feats2 = ws + 524288;              // 8192*16  = 131072
    float* pooled = ws + 655360;              // 64*16    = 1024
    int*   ctr    = (int*)(ws + 656384);      // 16 slots
    float* y_lc   = ws + 656400;              // 12288*16 = 196608
    float* n_lc   = ws + 853008;              // 12288
    float* y_f1   = ws + 865296;              // 12288*16 = 196608
    float* n_f1   = ws + 1061904;             // 12288   (end 1074192 fl = 4.1 MB)

    encode_kernel<<<(NTS + NLC) / 64, 256, 0, stream>>>(
        x_ts, x_lc, ts_w1, ts_b1, ts_w2, ts_b2, lc_w1, lc_b1, lc_w2, lc_b2,
        cw, ts_enc, lc_enc, y_lc, n_lc, pooled, ctr);

    edgeconv12_kernel<<<C1_BLOCKS + C2_BLOCKS, 512, CONV_SMEM_BYTES, stream>>>(
        lc_enc, y_lc, n_lc, ts_enc, cw, cb, feats1, y_f1, n_f1, feats2);

    edgeconv3_kernel<<<C2_BLOCKS, 512, CONV_SMEM_BYTES, stream>>>(
        feats1, y_f1, n_f1, feats2, cw, cb, pooled, ctr,
        ow1, ob1, ow2, ob2, ow3, ob3, ow4, ob4, ow5, ob5, out);
}

// Round 7
// 157.174 us; speedup vs baseline: 2.0015x; 2.0015x over previous
//
#include <hip/hip_runtime.h>
#include <math.h>

#define HID 16
#define KNN 16
#define NB 64          // graphs
#define NTS 8192
#define NLC 12288
#define TSG 128        // ts rows per graph
#define LCG 192        // lc rows per graph

__device__ __forceinline__ float eluf(float x) {
    return x > 0.0f ? x : expm1f(x);
}

// monotone map float -> uint32 (total order matches float <, incl. negatives)
__device__ __forceinline__ unsigned int f2ord(float f) {
    unsigned int b = __float_as_uint(f);
    return b ^ (((int)b >> 31) | 0x80000000u);
}

// ---------------------------------------------------------------- encoders
// 4 THREADS PER ROW (R6 change, kept: 320 blocks x 256 thr = 1280 waves vs
// R5's 80 blocks). Hidden vector relayed through LDS; accumulations all
// k-ascending -> bit-identical outputs (they feed kNN distance ties).
// Blocks 0..127 -> ts rows, 128..319 -> lc rows. Also zeroes pooled.
__global__ __launch_bounds__(256) void encode_kernel(
    const float* __restrict__ x_ts, const float* __restrict__ x_lc,
    const float* __restrict__ ts_w1, const float* __restrict__ ts_b1,
    const float* __restrict__ ts_w2, const float* __restrict__ ts_b2,
    const float* __restrict__ lc_w1, const float* __restrict__ lc_b1,
    const float* __restrict__ lc_w2, const float* __restrict__ lc_b2,
    const float* __restrict__ cw,
    float* __restrict__ ts_enc, float* __restrict__ lc_enc,
    float* __restrict__ y_lc, float* __restrict__ n_lc,
    float* __restrict__ pooled)
{
    __shared__ float sw1[6 * HID];
    __shared__ float sw2[HID * HID];
    __shared__ float scw2[HID * HID];   // conv W2 (lc blocks only)
    __shared__ float sb1[HID];
    __shared__ float sb2[HID];
    __shared__ float s_h[64 * 17];      // 64 rows/block, padded

    const int tid = threadIdx.x;
    const int t = blockIdx.x * 256 + tid;
    if (t < NB * HID) pooled[t] = 0.0f;   // zero pool accumulator (0xAA-poisoned)

    const bool is_ts = (blockIdx.x < NTS / 64);   // 128 ts blocks
    const float* w1 = is_ts ? ts_w1 : lc_w1;
    const float* b1 = is_ts ? ts_b1 : lc_b1;
    const float* w2 = is_ts ? ts_w2 : lc_w2;
    const float* b2 = is_ts ? ts_b2 : lc_b2;
    const int in_dim = is_ts ? 6 : 5;

    if (tid < in_dim * HID) sw1[tid] = w1[tid];
    if (tid < HID * HID)    sw2[tid] = w2[tid];
    if (!is_ts && tid < HID * HID) scw2[tid] = cw[HID * HID + tid];
    if (tid < HID)          { sb1[tid] = b1[tid]; sb2[tid] = b2[tid]; }
    __syncthreads();

    const int q    = tid & 3;          // channel quad: channels 4q..4q+3
    const int rloc = tid >> 2;         // local row 0..63
    const int row  = is_ts ? (blockIdx.x * 64 + rloc)
                           : ((blockIdx.x - 128) * 64 + rloc);
    const float* x = is_ts ? (x_ts + (size_t)row * 6) : (x_lc + (size_t)row * 5);
    float* outp    = is_ts ? (ts_enc + (size_t)row * HID) : (lc_enc + (size_t)row * HID);

    float xin[6];
    for (int k = 0; k < in_dim; ++k) xin[k] = x[k];

    // layer 1: this thread's 4 channels
    #pragma unroll
    for (int jc = 0; jc < 4; ++jc) {
        const int c = 4 * q + jc;
        float s = sb1[c];
        for (int k = 0; k < in_dim; ++k) s += xin[k] * sw1[k * HID + c];
        s_h[rloc * 17 + c] = eluf(s);
    }
    __syncthreads();
    float hf[HID];
    #pragma unroll
    for (int k = 0; k < HID; ++k) hf[k] = s_h[rloc * 17 + k];

    // layer 2
    float o4v[4];
    #pragma unroll
    for (int jc = 0; jc < 4; ++jc) {
        const int c = 4 * q + jc;
        float s = sb2[c];
        #pragma unroll
        for (int k = 0; k < HID; ++k) s += hf[k] * sw2[k * HID + c];
        o4v[jc] = eluf(s);
    }
    reinterpret_cast<float4*>(outp)[q] = make_float4(o4v[0], o4v[1], o4v[2], o4v[3]);

    if (!is_ts) {
        __syncthreads();   // done reading s_h (layer1); reuse for o relay
        #pragma unroll
        for (int jc = 0; jc < 4; ++jc) s_h[rloc * 17 + 4 * q + jc] = o4v[jc];
        __syncthreads();
        float of[HID];
        #pragma unroll
        for (int k = 0; k < HID; ++k) of[k] = s_h[rloc * 17 + k];
        float nv = 0.f;
        #pragma unroll
        for (int c = 0; c < HID; ++c) nv += of[c] * of[c];   // c ascending (exact self-dist 0)
        float y4[4];
        #pragma unroll
        for (int jc = 0; jc < 4; ++jc) {
            const int c = 4 * q + jc;
            float s = 0.f;
            #pragma unroll
            for (int k = 0; k < HID; ++k) s += of[k] * scw2[k * HID + c];
            y4[jc] = s;
        }
        reinterpret_cast<float4*>(y_lc + (size_t)row * HID)[q] =
            make_float4(y4[0], y4[1], y4[2], y4[3]);
        if (q == 0) n_lc[row] = nv;
    }
}

// ------------------------------------------------------------ edge conv
// ONE WAVE PER DST ROW; block = 512 threads = 8 dst rows of one graph.
// y = src@W2 and ||src||^2 precomputed. Lane keeps its 3 src rows
// {l, l+64, l+128} in registers. Top-16 SET via ballot-radix select
// (pure VALU/SALU — R5 win vs shuffle tournament), exact top_k tie-break.
// NOTE (R6 post-mortem): do NOT fuse a last-block head here — per-block
// __threadfence() on 1024 blocks serialized L2 writebacks (~185 us).
#define CONV_SMEM_FLOATS (LCG * HID + 2 * HID * HID + 2 * HID)
#define CONV_SMEM_BYTES  (CONV_SMEM_FLOATS * 4)

template<int NSRC, int NDST, bool POOL, bool EPI>
__device__ __forceinline__ void edgeconv_impl(
    float* __restrict__ smem, int bid,
    const float* __restrict__ src, const float* __restrict__ src_y,
    const float* __restrict__ src_n, const float* __restrict__ dst,
    const float* __restrict__ cw, const float* __restrict__ cb,
    float* __restrict__ out_feats, float* __restrict__ out_y,
    float* __restrict__ out_n, float* __restrict__ pool_out)
{
    constexpr int RPB = 8;              // dst rows (waves) per block
    constexpr int BPG = NDST / RPB;     // blocks per graph
    float* s_y    = smem;                        // NSRC*HID
    float* s_dw   = s_y + NSRC * HID;            // 256  (W1 - W2)
    float* s_w2   = s_dw + HID * HID;            // 256  (EPI only)
    float* s_b    = s_w2 + HID * HID;            // 16
    float* s_pool = s_b + HID;                   // 16

    const int tid  = threadIdx.x;
    const int lane = tid & 63;
    const int wave = tid >> 6;
    const int g      = bid / BPG;
    const int rowblk = bid % BPG;

    // ---- stage weights + y (coalesced float4)
    if (tid < HID * HID) {
        float w1v = cw[tid];
        float w2v = cw[HID * HID + tid];
        s_dw[tid] = w1v - w2v;
        if (EPI) s_w2[tid] = w2v;
    }
    if (tid < HID) s_b[tid] = cb[tid];
    if (POOL && tid < HID) s_pool[tid] = 0.0f;
    {
        const float4* gy = reinterpret_cast<const float4*>(src_y + (size_t)(g * NSRC) * HID);
        float4* sy4 = reinterpret_cast<float4*>(s_y);
        for (int i = tid; i < NSRC * HID / 4; i += 512) sy4[i] = gy[i];
    }

    // ---- own src rows + norms -> registers
    float rw[3][HID];
    float rn[3];
    #pragma unroll
    for (int k = 0; k < 3; ++k) {
        const float4* rp = reinterpret_cast<const float4*>(src + (size_t)(g * NSRC + lane + 64 * k) * HID);
        float4 a = rp[0], b = rp[1], c4 = rp[2], e = rp[3];
        rw[k][0] = a.x;  rw[k][1] = a.y;  rw[k][2]  = a.z;  rw[k][3]  = a.w;
        rw[k][4] = b.x;  rw[k][5] = b.y;  rw[k][6]  = b.z;  rw[k][7]  = b.w;
        rw[k][8] = c4.x; rw[k][9] = c4.y; rw[k][10] = c4.z; rw[k][11] = c4.w;
        rw[k][12] = e.x; rw[k][13] = e.y; rw[k][14] = e.z;  rw[k][15] = e.w;
        rn[k] = src_n[g * NSRC + lane + 64 * k];
    }

    // ---- my wave's dst row
    const int drow = rowblk * RPB + wave;
    const float4* d4 = reinterpret_cast<const float4*>(dst + (size_t)(g * NDST + drow) * HID);
    float xi[HID];
    {
        float4 a = d4[0], b = d4[1], c4 = d4[2], e = d4[3];
        xi[0] = a.x;  xi[1] = a.y;  xi[2]  = a.z;  xi[3]  = a.w;
        xi[4] = b.x;  xi[5] = b.y;  xi[6]  = b.z;  xi[7]  = b.w;
        xi[8] = c4.x; xi[9] = c4.y; xi[10] = c4.z; xi[11] = c4.w;
        xi[12] = e.x; xi[13] = e.y; xi[14] = e.z;  xi[15] = e.w;
    }
    float nd = 0.f;
    #pragma unroll
    for (int c = 0; c < HID; ++c) nd += xi[c] * xi[c];

    // ---- 3 candidate distances as ordered-u32 (idx implicit: lane + 64k)
    unsigned int dk0, dk1, dk2;
    {
        unsigned int dk[3];
        #pragma unroll
        for (int k = 0; k < 3; ++k) {
            float dot = 0.f;
            #pragma unroll
            for (int c = 0; c < HID; ++c) dot += xi[c] * rw[k][c];
            dk[k] = f2ord(nd - 2.0f * dot + rn[k]);
        }
        dk0 = dk[0]; dk1 = dk[1]; dk2 = dk[2];
    }

    // ---- ballot-radix select of the 16th-smallest (dist, idx) key
    unsigned int p = 0;
    int k = KNN;
    for (int b = 31; b >= 0; --b) {
        unsigned int pb = p >> b;
        int cnt = __popcll(__ballot((dk0 >> b) == pb))
                + __popcll(__ballot((dk1 >> b) == pb))
                + __popcll(__ballot((dk2 >> b) == pb));
        if (k > cnt) { k -= cnt; p |= (1u << b); }
    }
    int cnt_eq = __popcll(__ballot(dk0 == p))
               + __popcll(__ballot(dk1 == p))
               + __popcll(__ballot(dk2 == p));
    unsigned int qi = 255u;              // idx cutoff within eq class
    if (cnt_eq != k) {                   // rare exact-dist tie at the boundary
        qi = 0;
        int kk = k;
        const unsigned int i0 = (unsigned)lane, i1 = (unsigned)(lane + 64), i2 = (unsigned)(lane + 128);
        for (int b = 7; b >= 0; --b) {
            unsigned int qb = qi >> b;
            int cnt = __popcll(__ballot(dk0 == p && (i0 >> b) == qb))
                    + __popcll(__ballot(dk1 == p && (i1 >> b) == qb))
                    + __popcll(__ballot(dk2 == p && (i2 >> b) == qb));
            if (kk > cnt) { kk -= cnt; qi |= (1u << b); }
        }
    }
    unsigned long long m0 = __ballot(dk0 < p || (dk0 == p && (unsigned)lane <= qi));
    unsigned long long m1 = __ballot(dk1 < p || (dk1 == p && (unsigned)(lane + 64) <= qi));
    unsigned long long m2 = __ballot(dk2 < p || (dk2 == p && (unsigned)(lane + 128) <= qi));

    __syncthreads();   // s_y / s_dw ready

    // ci = b + xi @ (W1 - W2); lane handles channel c = lane & 15
    const int c = lane & 15;
    float cic = s_b[c];
    #pragma unroll
    for (int r = 0; r < HID; ++r) cic += xi[r] * s_dw[r * HID + c];

    // ---- winner indices (SALU, wave-uniform), then 16 independent y reads
    int jarr[KNN];
    #pragma unroll
    for (int i = 0; i < KNN; ++i) {
        int j;
        if (m0)      { j = __builtin_ctzll(m0);       m0 &= m0 - 1; }
        else if (m1) { j = 64 + __builtin_ctzll(m1);  m1 &= m1 - 1; }
        else         { j = 128 + __builtin_ctzll(m2); m2 &= m2 - 1; }
        jarr[i] = j;
    }
    float yv[KNN];
    #pragma unroll
    for (int i = 0; i < KNN; ++i) yv[i] = s_y[jarr[i] * HID + c];
    float ym = yv[0];
    #pragma unroll
    for (int i = 1; i < KNN; ++i) ym = fmaxf(ym, yv[i]);

    const float f = eluf(cic + ym);   // == max_j elu(ci + y_j), exact

    if (POOL) {
        if (lane < HID) atomicAdd(&s_pool[c], f);
        __syncthreads();
        if (tid < HID) atomicAdd(&pool_out[g * HID + tid], s_pool[tid]);
    } else {
        const int grow = g * NDST + drow;
        if (lane < HID) out_feats[(size_t)grow * HID + c] = f;
        if (EPI) {
            float yvv = 0.f, nv = 0.f;
            #pragma unroll
            for (int r = 0; r < HID; ++r) {
                float fr = __shfl(f, r, 64);   // lane r holds channel r
                yvv += fr * s_w2[r * HID + c];
                nv += fr * fr;
            }
            if (lane < HID) out_y[(size_t)grow * HID + c] = yvv;
            if (lane == 0)  out_n[grow] = nv;
        }
    }
}

// conv1 (lc->lc, emits y/n for conv3) and conv2 (lc->ts): independent -> one dispatch.
#define C1_BLOCKS (NB * (LCG / 8))   // 1536
#define C2_BLOCKS (NB * (TSG / 8))   // 1024
__global__ __launch_bounds__(512) void edgeconv12_kernel(
    const float* __restrict__ lc_enc, const float* __restrict__ y_lc,
    const float* __restrict__ n_lc, const float* __restrict__ ts_enc,
    const float* __restrict__ cw, const float* __restrict__ cb,
    float* __restrict__ feats1, float* __restrict__ y_f1, float* __restrict__ n_f1,
    float* __restrict__ feats2)
{
    extern __shared__ float smem[];
    if (blockIdx.x < C1_BLOCKS)
        edgeconv_impl<LCG, LCG, false, true>(smem, blockIdx.x, lc_enc, y_lc, n_lc,
                                             lc_enc, cw, cb, feats1, y_f1, n_f1, nullptr);
    else
        edgeconv_impl<LCG, TSG, false, false>(smem, blockIdx.x - C1_BLOCKS, lc_enc, y_lc, n_lc,
                                              ts_enc, cw, cb, feats2, nullptr, nullptr, nullptr);
}

__global__ __launch_bounds__(512) void edgeconv3_kernel(
    const float* __restrict__ feats1, const float* __restrict__ y_f1,
    const float* __restrict__ n_f1, const float* __restrict__ feats2,
    const float* __restrict__ cw, const float* __restrict__ cb,
    float* __restrict__ pooled)
{
    extern __shared__ float smem[];
    edgeconv_impl<LCG, TSG, true, false>(smem, blockIdx.x, feats1, y_f1, n_f1,
                                         feats2, cw, cb, nullptr, nullptr, nullptr, pooled);
}

// ---------------------------------------------------------------- head MLP
// One block per graph, lane-coalesced weight loads, LDS relay (R5 version).
__global__ __launch_bounds__(64) void head_kernel(
    const float* __restrict__ pooled,   // SUMS over 128 rows per graph
    const float* __restrict__ w1, const float* __restrict__ b1,
    const float* __restrict__ w2, const float* __restrict__ b2,
    const float* __restrict__ w3, const float* __restrict__ b3,
    const float* __restrict__ w4, const float* __restrict__ b4,
    const float* __restrict__ w5, const float* __restrict__ b5,
    float* __restrict__ out)
{
    const int g = blockIdx.x;
    const int lane = threadIdx.x;
    __shared__ float sp[HID];
    __shared__ float sh1[64];
    __shared__ float sh2[32];
    __shared__ float sh3[8];
    __shared__ float sh4[4];

    if (lane < HID) sp[lane] = pooled[g * HID + lane] * (1.0f / (float)TSG);
    __syncthreads();

    {
        float s = b1[lane];
        #pragma unroll
        for (int r = 0; r < HID; ++r) s += sp[r] * w1[r * 64 + lane];
        sh1[lane] = eluf(s);
    }
    __syncthreads();
    if (lane < 32) {
        float s = b2[lane];
        #pragma unroll
        for (int r = 0; r < 64; ++r) s += sh1[r] * w2[r * 32 + lane];
        sh2[lane] = eluf(s);
    }
    __syncthreads();
    if (lane < 8) {
        float s = b3[lane];
        #pragma unroll
        for (int r = 0; r < 32; ++r) s += sh2[r] * w3[r * 8 + lane];
        sh3[lane] = eluf(s);
    }
    __syncthreads();
    if (lane < 4) {
        float s = b4[lane];
        #pragma unroll
        for (int r = 0; r < 8; ++r) s += sh3[r] * w4[r * 4 + lane];
        sh4[lane] = eluf(s);
    }
    __syncthreads();
    if (lane == 0) {
        float s = b5[0];
        #pragma unroll
        for (int r = 0; r < 4; ++r) s += sh4[r] * w5[r];
        out[g] = s;
        out[NB + g] = (float)g;   // batch_out = arange(B)
    }
}

// ---------------------------------------------------------------- launch
extern "C" void kernel_launch(void* const* d_in, const int* in_sizes, int n_in,
                              void* d_out, int out_size, void* d_ws, size_t ws_size,
                              hipStream_t stream) {
    const float* x_ts  = (const float*)d_in[0];
    const float* x_lc  = (const float*)d_in[1];
    // d_in[2], d_in[3]: batch arrays — contiguous repeat(arange(64)), layout hard-coded
    const float* ts_w1 = (const float*)d_in[4];
    const float* ts_b1 = (const float*)d_in[5];
    const float* ts_w2 = (const float*)d_in[6];
    const float* ts_b2 = (const float*)d_in[7];
    const float* lc_w1 = (const float*)d_in[8];
    const float* lc_b1 = (const float*)d_in[9];
    const float* lc_w2 = (const float*)d_in[10];
    const float* lc_b2 = (const float*)d_in[11];
    const float* cw    = (const float*)d_in[12];
    const float* cb    = (const float*)d_in[13];
    const float* ow1   = (const float*)d_in[14];
    const float* ob1   = (const float*)d_in[15];
    const float* ow2   = (const float*)d_in[16];
    const float* ob2   = (const float*)d_in[17];
    const float* ow3   = (const float*)d_in[18];
    const float* ob3   = (const float*)d_in[19];
    const float* ow4   = (const float*)d_in[20];
    const float* ob4   = (const float*)d_in[21];
    const float* ow5   = (const float*)d_in[22];
    const float* ob5   = (const float*)d_in[23];
    float* out = (float*)d_out;

    float* ws = (float*)d_ws;
    float* ts_enc = ws;                       // 8192*16  = 131072
    float* lc_enc = ws + 131072;              // 12288*16 = 196608
    float* feats1 = ws + 327680;              // 12288*16 = 196608
    float* feats2 = ws + 524288;              // 8192*16  = 131072
    float* pooled = ws + 655360;              // 64*16    = 1024
    float* y_lc   = ws + 656384;              // 12288*16 = 196608
    float* n_lc   = ws + 852992;              // 12288
    float* y_f1   = ws + 865280;              // 12288*16 = 196608
    float* n_f1   = ws + 1061888;             // 12288   (end 1074176 fl = 4.1 MB)

    encode_kernel<<<(NTS + NLC) / 64, 256, 0, stream>>>(
        x_ts, x_lc, ts_w1, ts_b1, ts_w2, ts_b2, lc_w1, lc_b1, lc_w2, lc_b2,
        cw, ts_enc, lc_enc, y_lc, n_lc, pooled);

    edgeconv12_kernel<<<C1_BLOCKS + C2_BLOCKS, 512, CONV_SMEM_BYTES, stream>>>(
        lc_enc, y_lc, n_lc, ts_enc, cw, cb, feats1, y_f1, n_f1, feats2);

    edgeconv3_kernel<<<C2_BLOCKS, 512, CONV_SMEM_BYTES, stream>>>(
        feats1, y_f1, n_f1, feats2, cw, cb, pooled);

    head_kernel<<<NB, 64, 0, stream>>>(
        pooled, ow1, ob1, ow2, ob2, ow3, ob3, ow4, ob4, ow5, ob5, out);
}